// Round 4
// baseline (651.980 us; speedup 1.0000x reference)
//
#include <hip/hip_runtime.h>

#define N_BINS 15
#define NCLASS 128

typedef float fx4 __attribute__((ext_vector_type(4)));

__global__ void zero_out_kernel(float* __restrict__ out) {
    int i = threadIdx.x;
    if (i < 2 * N_BINS) out[i] = 0.0f;
}

// Cross-lane moves within an 8-lane octet.
// xor1/xor2 via DPP quad_perm (VALU pipe); xor4 via ds_swizzle (LDS pipe).
__device__ __forceinline__ int dpp_xor1_i(int x) {
    return __builtin_amdgcn_mov_dpp(x, 0xB1, 0xF, 0xF, true);  // [1,0,3,2]
}
__device__ __forceinline__ int dpp_xor2_i(int x) {
    return __builtin_amdgcn_mov_dpp(x, 0x4E, 0xF, 0xF, true);  // [2,3,0,1]
}
__device__ __forceinline__ int swz_xor4_i(int x) {
    return __builtin_amdgcn_ds_swizzle(x, 0x101F);  // bit-mode: xor=4, and=0x1F
}
__device__ __forceinline__ float dpp_xor1_f(float x) {
    return __int_as_float(dpp_xor1_i(__float_as_int(x)));
}
__device__ __forceinline__ float dpp_xor2_f(float x) {
    return __int_as_float(dpp_xor2_i(__float_as_int(x)));
}
__device__ __forceinline__ float swz_xor4_f(float x) {
    return __int_as_float(swz_xor4_i(__float_as_int(x)));
}

__global__ __launch_bounds__(256, 4) void conf_hist_kernel(
        const float* __restrict__ logits,
        const int* __restrict__ labels,
        float* __restrict__ out,
        int n) {
    __shared__ int hist[2 * N_BINS];
    if (threadIdx.x < 2 * N_BINS) hist[threadIdx.x] = 0;
    __syncthreads();

    const int lane = threadIdx.x & 63;
    const int oct = lane >> 3;   // 8 octets/wave; octet o handles samples base+o and base+8+o
    const int q8 = lane & 7;     // chunk within row: 8 lanes x 16B = full 128B cache line
    const int wavesPerBlock = blockDim.x >> 6;
    const int wave = blockIdx.x * wavesPerBlock + (threadIdx.x >> 6);
    const int numWaves = gridDim.x * wavesPerBlock;
    const int stride = numWaves * 16;  // 16 samples per wave-iteration

    // Per group (A: rows base..base+7, B: rows base+8..base+15):
    // load j=0..3: lane addr = row*512B + j*128B + q8*16B  -> 8 full 128B lines / instr
    // lane-local floats: global col = j*32 + q8*4 + e

    // ---- prologue: load iteration 0 ----
    int base = wave * 16;
    fx4 cA[8];   // [0..3] = group A chunks, [4..7] = group B chunks
    int labAa = 0, labAb = 0;
    {
        const int sA = base + oct;
        const int sB = base + 8 + oct;
        if (sA < n) {
            const float* rowA = logits + (size_t)sA * NCLASS + q8 * 4;
            #pragma unroll
            for (int j = 0; j < 4; ++j) cA[j] = *(const fx4*)(rowA + j * 32);
            labAa = labels[sA];
        }
        if (sB < n) {
            const float* rowB = logits + (size_t)sB * NCLASS + q8 * 4;
            #pragma unroll
            for (int j = 0; j < 4; ++j) cA[4 + j] = *(const fx4*)(rowB + j * 32);
            labAb = labels[sB];
        }
    }

    for (; base < n; base += stride) {
        // ---- software pipeline: issue NEXT iteration's loads first ----
        const int nbase = base + stride;
        fx4 cB[8];
        int labBa = 0, labBb = 0;
        {
            const int sA = nbase + oct;
            const int sB = nbase + 8 + oct;
            if (sA < n) {
                const float* rowA = logits + (size_t)sA * NCLASS + q8 * 4;
                #pragma unroll
                for (int j = 0; j < 4; ++j) cB[j] = *(const fx4*)(rowA + j * 32);
                labBa = labels[sA];
            }
            if (sB < n) {
                const float* rowB = logits + (size_t)sB * NCLASS + q8 * 4;
                #pragma unroll
                for (int j = 0; j < 4; ++j) cB[4 + j] = *(const fx4*)(rowB + j * 32);
                labBb = labels[sB];
            }
        }

        // ---- compute on buffer A (B's loads in flight) ----
        #pragma unroll
        for (int g = 0; g < 2; ++g) {
            const int s = base + g * 8 + oct;
            if (s < n) {
                const fx4* c = &cA[g * 4];
                const int lab = g ? labAb : labAa;

                // lane-local argmax over 16 values; strict > keeps lowest index
                float m[4]; int mi[4];
                #pragma unroll
                for (int j = 0; j < 4; ++j) {
                    float mm = c[j][0]; int ii = 0;
                    if (c[j][1] > mm) { mm = c[j][1]; ii = 1; }
                    if (c[j][2] > mm) { mm = c[j][2]; ii = 2; }
                    if (c[j][3] > mm) { mm = c[j][3]; ii = 3; }
                    m[j] = mm; mi[j] = j * 32 + q8 * 4 + ii;
                }
                if (m[1] > m[0]) { m[0] = m[1]; mi[0] = mi[1]; }
                if (m[3] > m[2]) { m[2] = m[3]; mi[2] = mi[3]; }
                if (m[2] > m[0]) { m[0] = m[2]; mi[0] = mi[2]; }
                float bm = m[0]; int bi = mi[0];

                // octet butterfly (xor1, xor2, xor4), tie-break by lower index
                {
                    float om = dpp_xor1_f(bm); int oi = dpp_xor1_i(bi);
                    if (om > bm || (om == bm && oi < bi)) { bm = om; bi = oi; }
                }
                {
                    float om = dpp_xor2_f(bm); int oi = dpp_xor2_i(bi);
                    if (om > bm || (om == bm && oi < bi)) { bm = om; bi = oi; }
                }
                {
                    float om = swz_xor4_f(bm); int oi = swz_xor4_i(bi);
                    if (om > bm || (om == bm && oi < bi)) { bm = om; bi = oi; }
                }

                // sum exp(l - max): lane-local pairwise, then butterfly
                float s4[4];
                #pragma unroll
                for (int j = 0; j < 4; ++j)
                    s4[j] = (__expf(c[j][0] - bm) + __expf(c[j][1] - bm))
                          + (__expf(c[j][2] - bm) + __expf(c[j][3] - bm));
                float e = (s4[0] + s4[1]) + (s4[2] + s4[3]);
                e += dpp_xor1_f(e);
                e += dpp_xor2_f(e);
                e += swz_xor4_f(e);

                if (q8 == 0) {
                    float conf = 1.0f / e;
                    int bin = (int)(conf * (float)N_BINS);
                    bin = bin > (N_BINS - 1) ? (N_BINS - 1) : (bin < 0 ? 0 : bin);
                    int col = (bi == lab) ? 0 : 1;  // col 0: correct
                    atomicAdd(&hist[bin * 2 + col], 1);
                }
            }
        }

        // ---- rotate buffers ----
        #pragma unroll
        for (int j = 0; j < 8; ++j) cA[j] = cB[j];
        labAa = labBa; labAb = labBb;
    }

    __syncthreads();
    if (threadIdx.x < 2 * N_BINS) {
        int c = hist[threadIdx.x];
        if (c != 0) atomicAdd(&out[threadIdx.x], (float)c);
    }
}

extern "C" void kernel_launch(void* const* d_in, const int* in_sizes, int n_in,
                              void* d_out, int out_size, void* d_ws, size_t ws_size,
                              hipStream_t stream) {
    const float* logits = (const float*)d_in[0];
    const int*   labels = (const int*)d_in[1];
    float* out = (float*)d_out;
    const int n = in_sizes[1];  // number of samples

    zero_out_kernel<<<1, 64, 0, stream>>>(out);

    const int block = 256;
    const int grid = 2048;  // 8192 waves, 4 waves/block
    conf_hist_kernel<<<grid, block, 0, stream>>>(logits, labels, out, n);
}